// Round 7
// baseline (173.592 us; speedup 1.0000x reference)
//
#include <hip/hip_runtime.h>
#include <hip/hip_bf16.h>
#include <stdint.h>

#define H_ 128
#define THREADS 256
#define EPB 64            // edges per block: 4 waves x 16
#define NBUCKET 8192
#define NPART 16
#define TS_SORT 1024

typedef __bf16 bf16x8 __attribute__((ext_vector_type(8)));
typedef float  f32x4  __attribute__((ext_vector_type(4)));

// wfrag layout (bf16 MFMA B-fragment order), idx = ks*4096 + nt*512 + lane*8 + j
//   k = ks*32 + (lane>>4)*8 + j   (K index into [zu|za] concat, 0..255)
//   n = nt*16 + (lane&15)         (output channel, 0..127)

__device__ inline bf16x8 pack8(float4 a, float4 b) {
    bf16x8 v;
    v[0] = (__bf16)a.x; v[1] = (__bf16)a.y; v[2] = (__bf16)a.z; v[3] = (__bf16)a.w;
    v[4] = (__bf16)b.x; v[5] = (__bf16)b.y; v[6] = (__bf16)b.z; v[7] = (__bf16)b.w;
    return v;
}

// prep: W1 -> bf16 fragment order (first 128 blocks), z_anime -> bf16.
__global__ void prep_kernel(const float* __restrict__ W1,
                            const float* __restrict__ za,
                            __bf16* __restrict__ wfrag,
                            __bf16* __restrict__ za_bf,
                            int nza) {
    int t = blockIdx.x * 256 + threadIdx.x;
    if (t < 32768) {
        int j  = t & 7;
        int ln = (t >> 3) & 63;
        int nt = (t >> 9) & 7;
        int ks = (t >> 12) & 7;
        int k  = ks * 32 + ((ln >> 4) << 3) + j;
        int n  = nt * 16 + (ln & 15);
        wfrag[t] = (__bf16)W1[k * H_ + n];
    } else {
        long i = (long)(t - 32768) * 8;
        if (i < nza) {
            float4 a = *(const float4*)(za + i);
            float4 b = *(const float4*)(za + i + 4);
            *(bf16x8*)(za_bf + i) = pack8(a, b);
        }
    }
}

// ---- fine-bucket counting sort (no global atomics) ------------------------
__global__ __launch_bounds__(TS_SORT)
void hist_kernel(const int* __restrict__ row, int* __restrict__ part,
                 int E, int shift) {
    __shared__ int h[NBUCKET];
    const int p = blockIdx.x, tid = threadIdx.x;
    #pragma unroll
    for (int j = 0; j < NBUCKET / TS_SORT; ++j) h[tid + j * TS_SORT] = 0;
    __syncthreads();
    const int chunk = (E + NPART - 1) / NPART;
    const int s = p * chunk, e = min(s + chunk, E);
    for (int i = s + tid; i < e; i += TS_SORT)
        atomicAdd(&h[row[i] >> shift], 1);
    __syncthreads();
    #pragma unroll
    for (int j = 0; j < NBUCKET / TS_SORT; ++j)
        part[p * NBUCKET + tid + j * TS_SORT] = h[tid + j * TS_SORT];
}

// scanA: bucket totals. grid = NBUCKET/256 blocks x 256.
__global__ void scanA_kernel(const int* __restrict__ part, int* __restrict__ btot) {
    int b = blockIdx.x * 256 + threadIdx.x;
    int s = 0;
    #pragma unroll 4
    for (int p = 0; p < NPART; ++p) s += part[p * NBUCKET + b];
    btot[b] = s;
}

// scanB: exclusive scan of NBUCKET totals. one block of 1024.
__global__ __launch_bounds__(1024)
void scanB_kernel(const int* __restrict__ btot, int* __restrict__ bbase) {
    __shared__ int wsum[16];
    const int t = threadIdx.x;
    int v[8]; int s = 0;
    #pragma unroll
    for (int j = 0; j < 8; ++j) { v[j] = btot[t * 8 + j]; s += v[j]; }
    const int lane = t & 63, wv = t >> 6;
    int inc = s;
    #pragma unroll
    for (int off = 1; off < 64; off <<= 1) {
        int x = __shfl_up(inc, off, 64);
        if (lane >= off) inc += x;
    }
    if (lane == 63) wsum[wv] = inc;
    __syncthreads();
    if (wv == 0 && lane < 16) {
        int ws = wsum[lane];
        #pragma unroll
        for (int off = 1; off < 16; off <<= 1) {
            int x = __shfl_up(ws, off, 64);
            if (lane >= off) ws += x;
        }
        wsum[lane] = ws;
    }
    __syncthreads();
    int excl = ((wv > 0) ? wsum[wv - 1] : 0) + inc - s;
    #pragma unroll
    for (int j = 0; j < 8; ++j) { bbase[t * 8 + j] = excl; excl += v[j]; }
}

// scanC: per-(part,bucket) slot bases.
__global__ void scanC_kernel(int* __restrict__ part, const int* __restrict__ bbase) {
    int b = blockIdx.x * 256 + threadIdx.x;
    int run = bbase[b];
    #pragma unroll 4
    for (int p = 0; p < NPART; ++p) {
        int idx = p * NBUCKET + b;
        int x = part[idx];
        part[idx] = run;
        run += x;
    }
}

__global__ __launch_bounds__(TS_SORT)
void scatter_kernel(const int* __restrict__ row, const int* __restrict__ col,
                    const int* __restrict__ part,
                    int* __restrict__ rowp, int* __restrict__ colp,
                    int* __restrict__ perm, int E, int shift) {
    __shared__ int pos[NBUCKET];
    const int p = blockIdx.x, tid = threadIdx.x;
    #pragma unroll
    for (int j = 0; j < NBUCKET / TS_SORT; ++j)
        pos[tid + j * TS_SORT] = part[p * NBUCKET + tid + j * TS_SORT];
    __syncthreads();
    const int chunk = (E + NPART - 1) / NPART;
    const int s = p * chunk, e = min(s + chunk, E);
    for (int i = s + tid; i < e; i += TS_SORT) {
        int r = row[i], c = col[i];
        int slot = atomicAdd(&pos[r >> shift], 1);
        rowp[slot] = r;
        colp[slot] = c;
        perm[slot] = i;
    }
}

__global__ __launch_bounds__(THREADS, 4)
void edge_decoder_kernel(const float* __restrict__ z_user,
                         const float* __restrict__ z_anime,
                         const int*   __restrict__ row,
                         const int*   __restrict__ col,
                         const int*   __restrict__ perm,   // null -> direct store
                         const float* __restrict__ W1,
                         const float* __restrict__ b1,
                         const float* __restrict__ W2,
                         const float* __restrict__ b2,
                         const __bf16* __restrict__ wfrag,
                         const __bf16* __restrict__ za_bf,
                         int use_ws,
                         float* __restrict__ out,
                         int E, int nwg) {
    // One K-phase of B fragments: [ks 0..3][nt][lane] of 8 bf16 = 32 KiB
    __shared__ bf16x8 Bf[4][8][64];

    // sorted mode: XCD-chunked bijective swizzle -> contiguous zu stream per XCD
    int wg = blockIdx.x;
    if (perm) {
        const int nx = 8;
        int q = nwg / nx, r = nwg % nx;
        int xcd = wg % nx, idx = wg / nx;
        int basewg = (xcd < r) ? xcd * (q + 1) : r * (q + 1) + (xcd - r) * q;
        wg = basewg + idx;
    }

    const int tid  = threadIdx.x;
    const int lane = tid & 63;
    const int wv   = tid >> 6;
    const int g    = lane >> 4;
    const int m    = lane & 15;
    const int base = wg * EPB + wv * 16;

    int e = base + m; if (e >= E) e = E - 1;
    const int r0 = row[e], c0 = col[e];

    // ---- issue ALL gathers up front: zu (fp32) + za (bf16 if prepped) ----
    float4 xu[8];
    {
        const float* zu = z_user + (size_t)r0 * H_ + g * 8;
        #pragma unroll
        for (int ks = 0; ks < 4; ++ks) {
            xu[2 * ks]     = *(const float4*)(zu + ks * 32);
            xu[2 * ks + 1] = *(const float4*)(zu + ks * 32 + 4);
        }
    }
    bf16x8 Aa[4];
    if (use_ws) {
        const __bf16* za = za_bf + (size_t)c0 * H_ + g * 8;
        #pragma unroll
        for (int ks = 0; ks < 4; ++ks)
            Aa[ks] = *(const bf16x8*)(za + ks * 32);
    }

    float w2v[8], b1v[8];
    #pragma unroll
    for (int nt = 0; nt < 8; ++nt) { int ch = nt * 16 + m; w2v[nt] = W2[ch]; b1v[nt] = b1[ch]; }
    const float bb = b2[0];

    // ---- stage W1 phase 0 (ks 0..3) ----
    if (use_ws) {
        const int4* src = (const int4*)wfrag;
        int4*       dst = (int4*)&Bf[0][0][0];
        #pragma unroll
        for (int i = 0; i < 8; ++i)
            dst[tid + i * THREADS] = src[tid + i * THREADS];
    } else {
        __bf16* d = (__bf16*)&Bf[0][0][0];
        for (int idx = tid; idx < H_ * H_; idx += THREADS) {
            int k = idx >> 7, n = idx & 127;
            int ks = k >> 5, gg = (k >> 3) & 3, j = k & 7;
            int nt = n >> 4, ln = (gg << 4) | (n & 15);
            d[ks * 4096 + nt * 512 + ln * 8 + j] = (__bf16)W1[k * H_ + n];
        }
    }
    __syncthreads();

    // pack zu -> A fragments (xu dies here)
    bf16x8 Au[4];
    #pragma unroll
    for (int ks = 0; ks < 4; ++ks)
        Au[ks] = pack8(xu[2 * ks], xu[2 * ks + 1]);

    f32x4 acc[8];
    #pragma unroll
    for (int nt = 0; nt < 8; ++nt) acc[nt] = (f32x4){0.f, 0.f, 0.f, 0.f};

    // ---- phase 0 MFMAs: zu @ W1[:128] ----
    #pragma unroll
    for (int nt = 0; nt < 8; ++nt) {
        #pragma unroll
        for (int ks = 0; ks < 4; ++ks) {
            bf16x8 b = Bf[ks][nt][lane];
            acc[nt] = __builtin_amdgcn_mfma_f32_16x16x32_bf16(Au[ks], b, acc[nt], 0, 0, 0);
        }
    }

    // fallback za path (fp32 load + pack) only when no workspace
    if (!use_ws) {
        const float* za = z_anime + (size_t)c0 * H_ + g * 8;
        #pragma unroll
        for (int ks = 0; ks < 4; ++ks)
            Aa[ks] = pack8(*(const float4*)(za + ks * 32),
                           *(const float4*)(za + ks * 32 + 4));
    }

    __syncthreads();   // phase-0 Bf reads complete before overwrite

    // ---- stage W1 phase 1 (ks 4..7) ----
    if (use_ws) {
        const int4* src = (const int4*)wfrag + 2048;   // 32 KiB offset
        int4*       dst = (int4*)&Bf[0][0][0];
        #pragma unroll
        for (int i = 0; i < 8; ++i)
            dst[tid + i * THREADS] = src[tid + i * THREADS];
    } else {
        __bf16* d = (__bf16*)&Bf[0][0][0];
        for (int idx = tid; idx < H_ * H_; idx += THREADS) {
            int k = idx >> 7, n = idx & 127;
            int ks = k >> 5, gg = (k >> 3) & 3, j = k & 7;
            int nt = n >> 4, ln = (gg << 4) | (n & 15);
            d[ks * 4096 + nt * 512 + ln * 8 + j] = (__bf16)W1[(H_ + k) * H_ + n];
        }
    }
    __syncthreads();

    // ---- phase 1 MFMAs: za @ W1[128:] ----
    #pragma unroll
    for (int nt = 0; nt < 8; ++nt) {
        #pragma unroll
        for (int ks = 0; ks < 4; ++ks) {
            bf16x8 b = Bf[ks][nt][lane];
            acc[nt] = __builtin_amdgcn_mfma_f32_16x16x32_bf16(Aa[ks], b, acc[nt], 0, 0, 0);
        }
    }

    // ---- epilogue: h = relu(acc + b1); out = h @ W2 + b2 ----
    float ps[4];
    #pragma unroll
    for (int r = 0; r < 4; ++r) {
        float s = 0.f;
        #pragma unroll
        for (int nt = 0; nt < 8; ++nt) {
            float h = acc[nt][r] + b1v[nt];
            s = fmaf(fmaxf(h, 0.f), w2v[nt], s);
        }
        ps[r] = s;
    }
    #pragma unroll
    for (int off = 1; off < 16; off <<= 1) {
        #pragma unroll
        for (int r = 0; r < 4; ++r)
            ps[r] += __shfl_xor(ps[r], off, 64);
    }
    if (m == 0) {
        int eb = base + g * 4;
        if (perm) {
            if (eb + 3 < E) {
                int4 p4 = *(const int4*)(perm + eb);
                out[p4.x] = ps[0] + bb;
                out[p4.y] = ps[1] + bb;
                out[p4.z] = ps[2] + bb;
                out[p4.w] = ps[3] + bb;
            } else {
                #pragma unroll
                for (int r = 0; r < 4; ++r)
                    if (eb + r < E) out[perm[eb + r]] = ps[r] + bb;
            }
        } else if (eb + 3 < E) {
            float4 o = make_float4(ps[0] + bb, ps[1] + bb, ps[2] + bb, ps[3] + bb);
            *(float4*)(out + eb) = o;
        } else {
            #pragma unroll
            for (int r = 0; r < 4; ++r)
                if (eb + r < E) out[eb + r] = ps[r] + bb;
        }
    }
}

extern "C" void kernel_launch(void* const* d_in, const int* in_sizes, int n_in,
                              void* d_out, int out_size, void* d_ws, size_t ws_size,
                              hipStream_t stream) {
    const float* z_user  = (const float*)d_in[0];
    const float* z_anime = (const float*)d_in[1];
    const int*   row     = (const int*)d_in[2];
    const int*   col     = (const int*)d_in[3];
    const float* W1      = (const float*)d_in[4];
    const float* b1      = (const float*)d_in[5];
    const float* W2      = (const float*)d_in[6];
    const float* b2      = (const float*)d_in[7];
    float*       out     = (float*)d_out;
    const int E   = in_sizes[2];
    const int nza = in_sizes[1];
    const int nu  = in_sizes[0] / H_;

    const int nb   = (E + EPB - 1) / EPB;
    const int Epad = nb * EPB;

    const size_t wfrag_bytes = 2u * H_ * H_ * sizeof(__bf16);           // 64 KiB
    const size_t za_bytes    = ((size_t)nza * sizeof(__bf16) + 255) & ~255ull;
    const size_t part_bytes  = (size_t)NPART * NBUCKET * sizeof(int);   // 512 KiB
    const size_t btot_bytes  = (size_t)NBUCKET * sizeof(int);
    const size_t idx_bytes   = ((size_t)Epad * sizeof(int) + 255) & ~255ull;

    const size_t need_basic = wfrag_bytes + za_bytes;
    const size_t need_sort  = need_basic + part_bytes + 2 * btot_bytes + 3 * idx_bytes;

    int use_ws   = (d_ws != nullptr && ws_size >= need_basic) ? 1 : 0;
    int use_sort = (d_ws != nullptr && ws_size >= need_sort) ? 1 : 0;

    char* p = (char*)d_ws;
    __bf16* wfrag = (__bf16*)p;   p += wfrag_bytes;
    __bf16* za_bf = (__bf16*)p;   p += za_bytes;
    int*    part  = (int*)p;      p += part_bytes;
    int*    btot  = (int*)p;      p += btot_bytes;
    int*    bbase = (int*)p;      p += btot_bytes;
    int*    rowp  = (int*)p;      p += idx_bytes;
    int*    colp  = (int*)p;      p += idx_bytes;
    int*    perm  = (int*)p;

    if (use_ws) {
        int za_threads = (nza + 7) / 8;
        int nb_prep = 128 + (za_threads + 255) / 256;
        prep_kernel<<<nb_prep, 256, 0, stream>>>(W1, z_anime, wfrag, za_bf, nza);
    }

    if (use_sort) {
        int shift = 0;
        while ((nu >> shift) >= NBUCKET) shift++;

        hist_kernel<<<NPART, TS_SORT, 0, stream>>>(row, part, E, shift);
        scanA_kernel<<<NBUCKET / 256, 256, 0, stream>>>(part, btot);
        scanB_kernel<<<1, 1024, 0, stream>>>(btot, bbase);
        scanC_kernel<<<NBUCKET / 256, 256, 0, stream>>>(part, bbase);
        scatter_kernel<<<NPART, TS_SORT, 0, stream>>>(row, col, part,
                                                      rowp, colp, perm, E, shift);

        edge_decoder_kernel<<<nb, THREADS, 0, stream>>>(
            z_user, z_anime, rowp, colp, perm, W1, b1, W2, b2,
            wfrag, za_bf, 1, out, E, nb);
    } else {
        edge_decoder_kernel<<<nb, THREADS, 0, stream>>>(
            z_user, z_anime, row, col, nullptr, W1, b1, W2, b2,
            wfrag, za_bf, use_ws, out, E, nb);
    }
}

// Round 8
// 75.232 us; speedup vs baseline: 2.3074x; 2.3074x over previous
//
#include <hip/hip_runtime.h>
#include <hip/hip_bf16.h>
#include <stdint.h>

#define H_ 128
#define NW 8
#define THREADS (NW * 64)   // 512
#define EPB 128             // 8 waves x 16 edges

typedef __bf16 bf16x8 __attribute__((ext_vector_type(8)));
typedef float  f32x4  __attribute__((ext_vector_type(4)));

// wfrag layout (bf16 MFMA B-fragment order), idx = ks*4096 + nt*512 + lane*8 + j
//   k = ks*32 + (lane>>4)*8 + j   (K index into [zu|za] concat, 0..255)
//   n = nt*16 + (lane&15)         (output channel, 0..127)
// Byte-linear: off = ks*8192 + nt*1024 + lane*16 + j*2  -> straight DMA copy.

__device__ inline bf16x8 pack8(float4 a, float4 b) {
    bf16x8 v;
    v[0] = (__bf16)a.x; v[1] = (__bf16)a.y; v[2] = (__bf16)a.z; v[3] = (__bf16)a.w;
    v[4] = (__bf16)b.x; v[5] = (__bf16)b.y; v[6] = (__bf16)b.z; v[7] = (__bf16)b.w;
    return v;
}

// prep: W1 -> bf16 fragment order (first 128 blocks), z_anime -> bf16.
__global__ void prep_kernel(const float* __restrict__ W1,
                            const float* __restrict__ za,
                            __bf16* __restrict__ wfrag,
                            __bf16* __restrict__ za_bf,
                            int nza) {
    int t = blockIdx.x * 256 + threadIdx.x;
    if (t < 32768) {
        int j  = t & 7;
        int ln = (t >> 3) & 63;
        int nt = (t >> 9) & 7;
        int ks = (t >> 12) & 7;
        int k  = ks * 32 + ((ln >> 4) << 3) + j;
        int n  = nt * 16 + (ln & 15);
        wfrag[t] = (__bf16)W1[k * H_ + n];
    } else {
        long i = (long)(t - 32768) * 8;
        if (i < nza) {
            float4 a = *(const float4*)(za + i);
            float4 b = *(const float4*)(za + i + 4);
            *(bf16x8*)(za_bf + i) = pack8(a, b);
        }
    }
}

// async global->LDS: 16B per lane; LDS dest = wave-uniform base + lane*16
#define GLD16(gp, lp) __builtin_amdgcn_global_load_lds(                      \
    (const __attribute__((address_space(1))) void*)(gp),                     \
    (__attribute__((address_space(3))) void*)(lp), 16, 0, 0)

__global__ __launch_bounds__(THREADS, 2)
void edge_decoder_kernel(const float* __restrict__ z_user,
                         const float* __restrict__ z_anime,
                         const int*   __restrict__ row,
                         const int*   __restrict__ col,
                         const float* __restrict__ W1,
                         const float* __restrict__ b1,
                         const float* __restrict__ W2,
                         const float* __restrict__ b2,
                         const __bf16* __restrict__ wfrag,
                         const __bf16* __restrict__ za_bf,
                         int use_ws,
                         float* __restrict__ out,
                         int E) {
    __shared__ bf16x8 Bf[8][8][64];   // full W1 fragments, 64 KiB

    const int tid  = threadIdx.x;
    const int lane = tid & 63;
    const int wv   = tid >> 6;
    const int g    = lane >> 4;
    const int m    = lane & 15;
    const int base = blockIdx.x * EPB + wv * 16;

    int e = base + m; if (e >= E) e = E - 1;
    const int r0 = row[e], c0 = col[e];

    // ---- issue gathers first: zu (fp32 -> regs) + za (bf16 -> regs) ----
    float4 xu[8];
    {
        const float* zu = z_user + (size_t)r0 * H_ + g * 8;
        #pragma unroll
        for (int ks = 0; ks < 4; ++ks) {
            xu[2 * ks]     = *(const float4*)(zu + ks * 32);
            xu[2 * ks + 1] = *(const float4*)(zu + ks * 32 + 4);
        }
    }
    bf16x8 Aa[4];
    if (use_ws) {
        const __bf16* za = za_bf + (size_t)c0 * H_ + g * 8;
        #pragma unroll
        for (int ks = 0; ks < 4; ++ks)
            Aa[ks] = *(const bf16x8*)(za + ks * 32);
    } else {
        const float* za = z_anime + (size_t)c0 * H_ + g * 8;
        #pragma unroll
        for (int ks = 0; ks < 4; ++ks)
            Aa[ks] = pack8(*(const float4*)(za + ks * 32),
                           *(const float4*)(za + ks * 32 + 4));
    }

    // ---- stage full W1 via async DMA (wave wv owns ks=wv chunk, 8 KiB) ----
    if (use_ws) {
        const char* src = (const char*)wfrag + wv * 8192 + lane * 16;
        char*       dst = (char*)&Bf[0][0][0] + wv * 8192;
        #pragma unroll
        for (int i = 0; i < 8; ++i)
            GLD16(src + i * 1024, dst + i * 1024);
    } else {
        __bf16* d = (__bf16*)&Bf[0][0][0];
        for (int idx = tid; idx < 2 * H_ * H_; idx += THREADS) {
            int k = idx >> 7, n = idx & 127;
            int ks = k >> 5, gg = (k >> 3) & 3, j = k & 7;
            int nt = n >> 4, ln = (gg << 4) | (n & 15);
            d[ks * 4096 + nt * 512 + ln * 8 + j] = (__bf16)W1[k * H_ + n];
        }
    }

    // pack zu -> A fragments while the DMA flies (waits only on zu loads)
    bf16x8 Au[4];
    #pragma unroll
    for (int ks = 0; ks < 4; ++ks)
        Au[ks] = pack8(xu[2 * ks], xu[2 * ks + 1]);

    __syncthreads();   // DMA drained, Bf ready

    f32x4 acc[8];
    #pragma unroll
    for (int nt = 0; nt < 8; ++nt) acc[nt] = (f32x4){0.f, 0.f, 0.f, 0.f};

    // ---- 64 MFMAs: [zu|za] @ W1 ----
    #pragma unroll
    for (int nt = 0; nt < 8; ++nt) {
        #pragma unroll
        for (int ks = 0; ks < 4; ++ks) {
            bf16x8 b = Bf[ks][nt][lane];
            acc[nt] = __builtin_amdgcn_mfma_f32_16x16x32_bf16(Au[ks], b, acc[nt], 0, 0, 0);
        }
        #pragma unroll
        for (int ks = 0; ks < 4; ++ks) {
            bf16x8 b = Bf[4 + ks][nt][lane];
            acc[nt] = __builtin_amdgcn_mfma_f32_16x16x32_bf16(Aa[ks], b, acc[nt], 0, 0, 0);
        }
    }

    // ---- epilogue: h = relu(acc + b1); out = h @ W2 + b2 ----
    // C/D layout: channel = nt*16 + m, edge-within-tile = g*4 + reg
    float w2v[8], b1v[8];
    #pragma unroll
    for (int nt = 0; nt < 8; ++nt) { int ch = nt * 16 + m; w2v[nt] = W2[ch]; b1v[nt] = b1[ch]; }
    const float bb = b2[0];

    float ps[4];
    #pragma unroll
    for (int r = 0; r < 4; ++r) {
        float s = 0.f;
        #pragma unroll
        for (int nt = 0; nt < 8; ++nt) {
            float h = acc[nt][r] + b1v[nt];
            s = fmaf(fmaxf(h, 0.f), w2v[nt], s);
        }
        ps[r] = s;
    }
    #pragma unroll
    for (int off = 1; off < 16; off <<= 1) {
        #pragma unroll
        for (int r = 0; r < 4; ++r)
            ps[r] += __shfl_xor(ps[r], off, 64);
    }
    if (m == 0) {
        int eb = base + g * 4;
        if (eb + 3 < E) {
            float4 o = make_float4(ps[0] + bb, ps[1] + bb, ps[2] + bb, ps[3] + bb);
            *(float4*)(out + eb) = o;
        } else {
            #pragma unroll
            for (int r = 0; r < 4; ++r)
                if (eb + r < E) out[eb + r] = ps[r] + bb;
        }
    }
}

extern "C" void kernel_launch(void* const* d_in, const int* in_sizes, int n_in,
                              void* d_out, int out_size, void* d_ws, size_t ws_size,
                              hipStream_t stream) {
    const float* z_user  = (const float*)d_in[0];
    const float* z_anime = (const float*)d_in[1];
    const int*   row     = (const int*)d_in[2];
    const int*   col     = (const int*)d_in[3];
    const float* W1      = (const float*)d_in[4];
    const float* b1      = (const float*)d_in[5];
    const float* W2      = (const float*)d_in[6];
    const float* b2      = (const float*)d_in[7];
    float*       out     = (float*)d_out;
    const int E   = in_sizes[2];
    const int nza = in_sizes[1];

    const size_t wfrag_bytes = 2u * H_ * H_ * sizeof(__bf16);   // 64 KiB
    const size_t need = wfrag_bytes + (size_t)nza * sizeof(__bf16);
    int use_ws = (d_ws != nullptr && ws_size >= need) ? 1 : 0;

    __bf16* wfrag = (__bf16*)d_ws;
    __bf16* za_bf = (__bf16*)((char*)d_ws + wfrag_bytes);

    if (use_ws) {
        int za_threads = (nza + 7) / 8;
        int nb_prep = 128 + (za_threads + 255) / 256;
        prep_kernel<<<nb_prep, 256, 0, stream>>>(W1, z_anime, wfrag, za_bf, nza);
    }

    int nb = (E + EPB - 1) / EPB;
    edge_decoder_kernel<<<nb, THREADS, 0, stream>>>(
        z_user, z_anime, row, col, W1, b1, W2, b2,
        wfrag, za_bf, use_ws, out, E);
}